// Round 1
// baseline (3500.377 us; speedup 1.0000x reference)
//
#include <hip/hip_runtime.h>
#include <hip/hip_bf16.h>

#define NB 16
#define NN 4096
#define NPTS 512
#define NSAMP 64
#define BN_EPS 1e-5f

// ---------------------------------------------------------------------------
// FPS: one block per batch. Coords staged in LDS. Bit-exact vs numpy:
// d = ((dx*dx + dy*dy) + dz*dz) with _rn ops (no FMA contraction),
// argmax tie-break = smallest index (np.argmax first occurrence).
// ---------------------------------------------------------------------------
__global__ __launch_bounds__(1024) void fps_kernel(const float* __restrict__ coord,
                                                   int* __restrict__ cent) {
    __shared__ float sx[NN], sy[NN], sz[NN];
    __shared__ float swv[16];
    __shared__ int   swi[16];
    __shared__ int   sfar;
    const int b = blockIdx.x;
    const float* cb = coord + (size_t)b * NN * 3;
    const int t = threadIdx.x;

    for (int p = t; p < NN; p += 1024) {
        sx[p] = cb[p * 3 + 0];
        sy[p] = cb[p * 3 + 1];
        sz[p] = cb[p * 3 + 2];
    }
    float dist[4];
    int   pid[4];
#pragma unroll
    for (int k = 0; k < 4; ++k) { pid[k] = t + k * 1024; dist[k] = 1e10f; }
    if (t == 0) sfar = 0;
    __syncthreads();

    const int lane = t & 63;
    const int wid  = t >> 6;

    for (int it = 0; it < NPTS; ++it) {
        const int far = sfar;
        if (t == 0) cent[b * NPTS + it] = far;
        const float cx = sx[far], cy = sy[far], cz = sz[far];
        float bv = -1.0f;
        int   bi = 0x7fffffff;
#pragma unroll
        for (int k = 0; k < 4; ++k) {
            const int p = pid[k];
            const float dx = sx[p] - cx;
            const float dy = sy[p] - cy;
            const float dz = sz[p] - cz;
            const float d = __fadd_rn(__fadd_rn(__fmul_rn(dx, dx), __fmul_rn(dy, dy)),
                                      __fmul_rn(dz, dz));
            const float nd = fminf(dist[k], d);
            dist[k] = nd;
            if (nd > bv || (nd == bv && p < bi)) { bv = nd; bi = p; }
        }
        // wave argmax reduce (tie -> smaller index)
#pragma unroll
        for (int m = 1; m < 64; m <<= 1) {
            const float ov = __shfl_xor(bv, m);
            const int   oi = __shfl_xor(bi, m);
            if (ov > bv || (ov == bv && oi < bi)) { bv = ov; bi = oi; }
        }
        if (lane == 0) { swv[wid] = bv; swi[wid] = bi; }
        __syncthreads();
        if (t == 0) {
            float v = swv[0]; int i = swi[0];
            for (int w = 1; w < 16; ++w) {
                const float ov = swv[w]; const int oi = swi[w];
                if (ov > v || (ov == v && oi < i)) { v = ov; i = oi; }
            }
            sfar = i;
        }
        __syncthreads();
    }
}

// ---------------------------------------------------------------------------
// Ball query: one wave per sample. Scan 64-index chunks in ascending order,
// ballot + prefix-popcount gives the sorted first-64 semantics directly.
// sq replicated exactly: -2*dot + ssum + csum (each _rn, ref op order).
// ---------------------------------------------------------------------------
__global__ __launch_bounds__(256) void ball_kernel(const float* __restrict__ coord,
                                                   const int* __restrict__ cent,
                                                   float* __restrict__ gout) {
    const int gw   = blockIdx.x * 4 + (threadIdx.x >> 6); // sample id in [0, 8192)
    const int lane = threadIdx.x & 63;
    const int b = gw >> 9;
    const int s = gw & 511;
    const float* cb = coord + (size_t)b * NN * 3;
    const int ci = cent[b * NPTS + s];
    const float sxv = cb[ci * 3 + 0], syv = cb[ci * 3 + 1], szv = cb[ci * 3 + 2];
    const float ssum = __fadd_rn(__fadd_rn(__fmul_rn(sxv, sxv), __fmul_rn(syv, syv)),
                                 __fmul_rn(szv, szv));
    float* out = gout + (size_t)gw * NSAMP;
    int total = 0;
    int first = 0;

    for (int c = 0; c < NN / 64; ++c) {
        const int p = c * 64 + lane;
        const float cx = cb[p * 3 + 0], cyv = cb[p * 3 + 1], cz = cb[p * 3 + 2];
        const float csum = __fadd_rn(__fadd_rn(__fmul_rn(cx, cx), __fmul_rn(cyv, cyv)),
                                     __fmul_rn(cz, cz));
        const float dot = __fadd_rn(__fadd_rn(__fmul_rn(sxv, cx), __fmul_rn(syv, cyv)),
                                    __fmul_rn(szv, cz));
        float d = __fmul_rn(-2.0f, dot);
        d = __fadd_rn(d, ssum);
        d = __fadd_rn(d, csum);
        const bool keep = !(d > 0.16f);
        const unsigned long long mask = __ballot(keep);
        if (total == 0 && mask) first = c * 64 + (int)__builtin_ctzll(mask);
        if (keep) {
            const int rank = total + __popcll(mask & ((1ull << lane) - 1ull));
            if (rank < NSAMP) out[rank] = (float)p;
        }
        total += (int)__popcll(mask);
        if (total >= NSAMP) break;
    }
    if (total < NSAMP) {
        for (int pos = total + lane; pos < NSAMP; pos += 64) out[pos] = (float)first;
    }
}

// ---------------------------------------------------------------------------
// MLP layer: column-per-thread GEMM, W in LDS, per-channel sum/sumsq stats
// via wave shfl reduce + global atomics. Non-first layers apply the previous
// layer's fused BN scale/shift + ReLU on input load.
// ---------------------------------------------------------------------------
template <int CIN, int COUT, bool COORD_IN>
__global__ __launch_bounds__(256) void mlp_kernel(const float* __restrict__ X,
                                                  const float* __restrict__ W,
                                                  const float* __restrict__ Bias,
                                                  const float* __restrict__ AC,
                                                  float* __restrict__ Y,
                                                  float* __restrict__ stats) {
    __shared__ float sW[COUT * CIN];
    const int t = threadIdx.x;
    for (int i = t; i < COUT * CIN; i += 256) sW[i] = W[i];
    __syncthreads();

    const int col = blockIdx.x * 256 + t;   // in [0, B*N)
    const int b = col >> 12;
    const int n = col & 4095;
    const int lane = t & 63;

    float x[CIN];
    if (COORD_IN) {
#pragma unroll
        for (int ci = 0; ci < CIN; ++ci) x[ci] = X[(size_t)col * 3 + ci];
    } else {
#pragma unroll
        for (int ci = 0; ci < CIN; ++ci) {
            const float v = X[((size_t)b * CIN + ci) * NN + n];
            x[ci] = fmaxf(fmaf(v, AC[2 * ci], AC[2 * ci + 1]), 0.0f);
        }
    }

    for (int co = 0; co < COUT; ++co) {
        float acc = Bias[co];
#pragma unroll
        for (int ci = 0; ci < CIN; ++ci) acc = fmaf(x[ci], sW[co * CIN + ci], acc);
        Y[((size_t)b * COUT + co) * NN + n] = acc;
        float s = acc, s2 = acc * acc;
#pragma unroll
        for (int m = 1; m < 64; m <<= 1) {
            s  += __shfl_xor(s, m);
            s2 += __shfl_xor(s2, m);
        }
        if (lane == 0) {
            atomicAdd(&stats[2 * co], s);
            atomicAdd(&stats[2 * co + 1], s2);
        }
    }
}

__global__ void finalize_bn(const float* __restrict__ stats,
                            const float* __restrict__ g,
                            const float* __restrict__ be,
                            float* __restrict__ AC, int C, float inv_count) {
    const int c = blockIdx.x * blockDim.x + threadIdx.x;
    if (c < C) {
        const float mean = stats[2 * c] * inv_count;
        const float var  = stats[2 * c + 1] * inv_count - mean * mean;
        const float rstd = rsqrtf(var + BN_EPS);
        const float A = g[c] * rstd;
        AC[2 * c]     = A;
        AC[2 * c + 1] = be[c] - mean * A;
    }
}

__global__ __launch_bounds__(256) void apply_bn_relu(float* __restrict__ Y,
                                                     const float* __restrict__ AC) {
    const size_t i = (size_t)blockIdx.x * 256 + threadIdx.x; // over B*128*N
    const int c = (int)((i >> 12) & 127);
    const float v = Y[i];
    Y[i] = fmaxf(fmaf(v, AC[2 * c], AC[2 * c + 1]), 0.0f);
}

extern "C" void kernel_launch(void* const* d_in, const int* in_sizes, int n_in,
                              void* d_out, int out_size, void* d_ws, size_t ws_size,
                              hipStream_t stream) {
    const float* coord = (const float*)d_in[0];
    const float* w0  = (const float*)d_in[1];
    const float* b0  = (const float*)d_in[2];
    const float* g0  = (const float*)d_in[3];
    const float* be0 = (const float*)d_in[4];
    const float* w1  = (const float*)d_in[5];
    const float* b1  = (const float*)d_in[6];
    const float* g1  = (const float*)d_in[7];
    const float* be1 = (const float*)d_in[8];
    const float* w2  = (const float*)d_in[9];
    const float* b2  = (const float*)d_in[10];
    const float* g2  = (const float*)d_in[11];
    const float* be2 = (const float*)d_in[12];

    float* ws = (float*)d_ws;
    float* stats1 = ws;            // 128
    float* stats2 = ws + 128;      // 128
    float* stats3 = ws + 256;      // 256
    float* AC1 = ws + 512;         // 128
    float* AC2 = ws + 640;         // 128
    float* AC3 = ws + 768;         // 256
    int*   cent = (int*)(ws + 1024);                    // 16*512 ints
    float* a1 = (float*)((char*)d_ws + 65536);          // 16*64*4096
    float* a2 = a1 + (size_t)NB * 64 * NN;              // 16*64*4096

    float* gout  = (float*)d_out;                       // 16*512*64 (indices as float)
    float* feats = (float*)d_out + (size_t)NB * NPTS * NSAMP;

    const float invBN = 1.0f / (float)(NB * NN);

    hipMemsetAsync(d_ws, 0, 2048, stream);  // zero stats only

    fps_kernel<<<NB, 1024, 0, stream>>>(coord, cent);
    ball_kernel<<<(NB * NPTS) / 4, 256, 0, stream>>>(coord, cent, gout);

    mlp_kernel<3, 64, true><<<(NB * NN) / 256, 256, 0, stream>>>(coord, w0, b0, nullptr, a1, stats1);
    finalize_bn<<<1, 64, 0, stream>>>(stats1, g0, be0, AC1, 64, invBN);
    mlp_kernel<64, 64, false><<<(NB * NN) / 256, 256, 0, stream>>>(a1, w1, b1, AC1, a2, stats2);
    finalize_bn<<<1, 64, 0, stream>>>(stats2, g1, be1, AC2, 64, invBN);
    mlp_kernel<64, 128, false><<<(NB * NN) / 256, 256, 0, stream>>>(a2, w2, b2, AC2, feats, stats3);
    finalize_bn<<<1, 128, 0, stream>>>(stats3, g2, be2, AC3, 128, invBN);
    apply_bn_relu<<<(NB * 128 * NN) / 256, 256, 0, stream>>>(feats, AC3);
}

// Round 2
// 611.108 us; speedup vs baseline: 5.7279x; 5.7279x over previous
//
#include <hip/hip_runtime.h>
#include <hip/hip_bf16.h>

#define NB 16
#define NN 4096
#define NPTS 512
#define NSAMP 64
#define BN_EPS 1e-5f

// ---------------------------------------------------------------------------
// FPS: one block per batch, 512 threads, 8 points/thread held in registers.
// LDS float4 copy used only for the (uniform-address, broadcast) centroid
// fetch. Argmax via packed u64 key: (dist_bits << 32) | (NN-1-p) -> max key
// is max dist with smallest index (np.argmax first-occurrence), exact for
// nonneg f32. One barrier per step via double-buffered per-wave slots.
// Math bit-identical to numpy ref: ((dx*dx+dy*dy)+dz*dz), _rn ops, fminf.
// ---------------------------------------------------------------------------
__global__ __launch_bounds__(512) void fps_kernel(const float* __restrict__ coord,
                                                  int* __restrict__ cent) {
    __shared__ float4 sc[NN];                    // 64 KB
    __shared__ unsigned long long skey[2][8];
    const int b = blockIdx.x;
    const float* cb = coord + (size_t)b * NN * 3;
    const int t = threadIdx.x;

    for (int i = t; i < NN; i += 512)
        sc[i] = make_float4(cb[i * 3 + 0], cb[i * 3 + 1], cb[i * 3 + 2], 0.0f);
    __syncthreads();

    float x[8], y[8], z[8], dist[8];
#pragma unroll
    for (int k = 0; k < 8; ++k) {
        const float4 v = sc[t + k * 512];
        x[k] = v.x; y[k] = v.y; z[k] = v.z; dist[k] = 1e10f;
    }
    const int lane = t & 63;
    const int wid  = t >> 6;
    int far = 0;

    for (int it = 0; it < NPTS; ++it) {
        if (t == 0) cent[b * NPTS + it] = far;
        const float4 c = sc[far];                 // broadcast ds_read_b128
        unsigned long long bk = 0ull;
#pragma unroll
        for (int k = 0; k < 8; ++k) {
            const float dx = x[k] - c.x;
            const float dy = y[k] - c.y;
            const float dz = z[k] - c.z;
            const float d = __fadd_rn(__fadd_rn(__fmul_rn(dx, dx), __fmul_rn(dy, dy)),
                                      __fmul_rn(dz, dz));
            const float nd = fminf(dist[k], d);
            dist[k] = nd;
            const unsigned long long key =
                ((unsigned long long)__float_as_uint(nd) << 32) |
                (unsigned)(NN - 1 - (t + k * 512));
            bk = key > bk ? key : bk;
        }
#pragma unroll
        for (int m = 1; m < 64; m <<= 1) {
            const unsigned long long ok = __shfl_xor(bk, m);
            bk = ok > bk ? ok : bk;
        }
        if (lane == 0) skey[it & 1][wid] = bk;
        __syncthreads();
        unsigned long long mx = skey[it & 1][0];
#pragma unroll
        for (int w = 1; w < 8; ++w) {
            const unsigned long long o = skey[it & 1][w];
            mx = o > mx ? o : mx;
        }
        far = NN - 1 - (int)(mx & 0xffffffffull);
    }
}

// ---------------------------------------------------------------------------
// Ball query: one wave per sample (validated bit-exact in round 1).
// ---------------------------------------------------------------------------
__global__ __launch_bounds__(256) void ball_kernel(const float* __restrict__ coord,
                                                   const int* __restrict__ cent,
                                                   float* __restrict__ gout) {
    const int gw   = blockIdx.x * 4 + (threadIdx.x >> 6);
    const int lane = threadIdx.x & 63;
    const int b = gw >> 9;
    const int s = gw & 511;
    const float* cb = coord + (size_t)b * NN * 3;
    const int ci = cent[b * NPTS + s];
    const float sxv = cb[ci * 3 + 0], syv = cb[ci * 3 + 1], szv = cb[ci * 3 + 2];
    const float ssum = __fadd_rn(__fadd_rn(__fmul_rn(sxv, sxv), __fmul_rn(syv, syv)),
                                 __fmul_rn(szv, szv));
    float* out = gout + (size_t)gw * NSAMP;
    int total = 0;
    int first = 0;

    for (int c = 0; c < NN / 64; ++c) {
        const int p = c * 64 + lane;
        const float cx = cb[p * 3 + 0], cyv = cb[p * 3 + 1], cz = cb[p * 3 + 2];
        const float csum = __fadd_rn(__fadd_rn(__fmul_rn(cx, cx), __fmul_rn(cyv, cyv)),
                                     __fmul_rn(cz, cz));
        const float dot = __fadd_rn(__fadd_rn(__fmul_rn(sxv, cx), __fmul_rn(syv, cyv)),
                                    __fmul_rn(szv, cz));
        float d = __fmul_rn(-2.0f, dot);
        d = __fadd_rn(d, ssum);
        d = __fadd_rn(d, csum);
        const bool keep = !(d > 0.16f);
        const unsigned long long mask = __ballot(keep);
        if (total == 0 && mask) first = c * 64 + (int)__builtin_ctzll(mask);
        if (keep) {
            const int rank = total + __popcll(mask & ((1ull << lane) - 1ull));
            if (rank < NSAMP) out[rank] = (float)p;
        }
        total += (int)__popcll(mask);
        if (total >= NSAMP) break;
    }
    if (total < NSAMP) {
        for (int pos = total + lane; pos < NSAMP; pos += 64) out[pos] = (float)first;
    }
}

// ---------------------------------------------------------------------------
// MLP GEMM: pure column-per-thread, W-chunk in LDS, channel chunk per
// blockIdx.y (raises blocks/CU). Stats moved to a separate kernel.
// ---------------------------------------------------------------------------
template <int CIN, int COUT, int CHB, bool COORD_IN>
__global__ __launch_bounds__(256) void mlp_kernel(const float* __restrict__ X,
                                                  const float* __restrict__ W,
                                                  const float* __restrict__ Bias,
                                                  const float* __restrict__ AC,
                                                  float* __restrict__ Y) {
    __shared__ float sW[CHB * CIN];
    __shared__ float sB[CHB];
    const int t = threadIdx.x;
    const int c0 = blockIdx.y * CHB;
    for (int i = t; i < CHB * CIN; i += 256) sW[i] = W[(c0 + i / CIN) * CIN + (i % CIN)];
    if (t < CHB) sB[t] = Bias[c0 + t];
    __syncthreads();

    const int col = blockIdx.x * 256 + t;
    const int b = col >> 12;
    const int n = col & 4095;

    float x[CIN];
    if (COORD_IN) {
#pragma unroll
        for (int ci = 0; ci < CIN; ++ci) x[ci] = X[(size_t)col * 3 + ci];
    } else {
#pragma unroll
        for (int ci = 0; ci < CIN; ++ci) {
            const float v = X[((size_t)b * CIN + ci) * NN + n];
            x[ci] = fmaxf(fmaf(v, AC[2 * ci], AC[2 * ci + 1]), 0.0f);
        }
    }

#pragma unroll 4
    for (int co = 0; co < CHB; ++co) {
        float acc = sB[co];
#pragma unroll
        for (int ci = 0; ci < CIN; ++ci) acc = fmaf(x[ci], sW[co * CIN + ci], acc);
        Y[((size_t)b * COUT + c0 + co) * NN + n] = acc;
    }
}

// Per-channel sum/sumsq: block (c,b) reduces one contiguous 4096-float row.
template <int C>
__global__ __launch_bounds__(256) void stats_kernel(const float* __restrict__ Y,
                                                    float* __restrict__ stats) {
    const int c = blockIdx.x, b = blockIdx.y;
    const float4* row = (const float4*)(Y + ((size_t)b * C + c) * NN);
    const int t = threadIdx.x;
    float s = 0.0f, s2 = 0.0f;
#pragma unroll
    for (int i = 0; i < 4; ++i) {
        const float4 v = row[t + i * 256];
        s  += v.x + v.y + v.z + v.w;
        s2 += v.x * v.x + v.y * v.y + v.z * v.z + v.w * v.w;
    }
#pragma unroll
    for (int m = 1; m < 64; m <<= 1) { s += __shfl_xor(s, m); s2 += __shfl_xor(s2, m); }
    __shared__ float red[2][4];
    const int lane = t & 63, wid = t >> 6;
    if (lane == 0) { red[0][wid] = s; red[1][wid] = s2; }
    __syncthreads();
    if (t == 0) {
        const float S  = red[0][0] + red[0][1] + red[0][2] + red[0][3];
        const float S2 = red[1][0] + red[1][1] + red[1][2] + red[1][3];
        atomicAdd(&stats[2 * c], S);
        atomicAdd(&stats[2 * c + 1], S2);
    }
}

__global__ void finalize_bn(const float* __restrict__ stats,
                            const float* __restrict__ g,
                            const float* __restrict__ be,
                            float* __restrict__ AC, int C, float inv_count) {
    const int c = blockIdx.x * blockDim.x + threadIdx.x;
    if (c < C) {
        const float mean = stats[2 * c] * inv_count;
        const float var  = stats[2 * c + 1] * inv_count - mean * mean;
        const float rstd = rsqrtf(var + BN_EPS);
        const float A = g[c] * rstd;
        AC[2 * c]     = A;
        AC[2 * c + 1] = be[c] - mean * A;
    }
}

__global__ __launch_bounds__(256) void apply_bn_relu(float* __restrict__ Y,
                                                     const float* __restrict__ AC) {
    const size_t i = (size_t)blockIdx.x * 256 + threadIdx.x;  // float4 index
    const int c = (int)((i >> 10) & 127);
    float4 v = ((float4*)Y)[i];
    const float A = AC[2 * c], Bc = AC[2 * c + 1];
    v.x = fmaxf(fmaf(v.x, A, Bc), 0.0f);
    v.y = fmaxf(fmaf(v.y, A, Bc), 0.0f);
    v.z = fmaxf(fmaf(v.z, A, Bc), 0.0f);
    v.w = fmaxf(fmaf(v.w, A, Bc), 0.0f);
    ((float4*)Y)[i] = v;
}

extern "C" void kernel_launch(void* const* d_in, const int* in_sizes, int n_in,
                              void* d_out, int out_size, void* d_ws, size_t ws_size,
                              hipStream_t stream) {
    const float* coord = (const float*)d_in[0];
    const float* w0  = (const float*)d_in[1];
    const float* b0  = (const float*)d_in[2];
    const float* g0  = (const float*)d_in[3];
    const float* be0 = (const float*)d_in[4];
    const float* w1  = (const float*)d_in[5];
    const float* b1  = (const float*)d_in[6];
    const float* g1  = (const float*)d_in[7];
    const float* be1 = (const float*)d_in[8];
    const float* w2  = (const float*)d_in[9];
    const float* b2  = (const float*)d_in[10];
    const float* g2  = (const float*)d_in[11];
    const float* be2 = (const float*)d_in[12];

    float* ws = (float*)d_ws;
    float* stats1 = ws;            // 128
    float* stats2 = ws + 128;      // 128
    float* stats3 = ws + 256;      // 256
    float* AC1 = ws + 512;         // 128
    float* AC2 = ws + 640;         // 128
    float* AC3 = ws + 768;         // 256
    int*   cent = (int*)(ws + 1024);                    // 16*512 ints
    float* a1 = (float*)((char*)d_ws + 65536);          // 16*64*4096
    float* a2 = a1 + (size_t)NB * 64 * NN;              // 16*64*4096

    float* gout  = (float*)d_out;
    float* feats = (float*)d_out + (size_t)NB * NPTS * NSAMP;

    const float invBN = 1.0f / (float)(NB * NN);

    hipMemsetAsync(d_ws, 0, 2048, stream);  // zero stats only

    fps_kernel<<<NB, 512, 0, stream>>>(coord, cent);
    ball_kernel<<<(NB * NPTS) / 4, 256, 0, stream>>>(coord, cent, gout);

    mlp_kernel<3, 64, 32, true><<<dim3((NB * NN) / 256, 2), 256, 0, stream>>>(coord, w0, b0, nullptr, a1);
    stats_kernel<64><<<dim3(64, NB), 256, 0, stream>>>(a1, stats1);
    finalize_bn<<<1, 64, 0, stream>>>(stats1, g0, be0, AC1, 64, invBN);

    mlp_kernel<64, 64, 32, false><<<dim3((NB * NN) / 256, 2), 256, 0, stream>>>(a1, w1, b1, AC1, a2);
    stats_kernel<64><<<dim3(64, NB), 256, 0, stream>>>(a2, stats2);
    finalize_bn<<<1, 64, 0, stream>>>(stats2, g1, be1, AC2, 64, invBN);

    mlp_kernel<64, 128, 64, false><<<dim3((NB * NN) / 256, 2), 256, 0, stream>>>(a2, w2, b2, AC2, feats);
    stats_kernel<128><<<dim3(128, NB), 256, 0, stream>>>(feats, stats3);
    finalize_bn<<<1, 128, 0, stream>>>(stats3, g2, be2, AC3, 128, invBN);

    apply_bn_relu<<<(NB * 128 * NN) / (256 * 4), 256, 0, stream>>>(feats, AC3);
}